// Round 1
// baseline (200.013 us; speedup 1.0000x reference)
//
#include <hip/hip_runtime.h>

#define HH 32      // LSTM hidden
#define NN 64      // feature dim (2*H)
#define TMAX 512   // max T supported by LDS score buffer

__device__ __forceinline__ float sigmoidf_(float x) {
    return 1.0f / (1.0f + __expf(-x));
}
__device__ __forceinline__ float ftanh(float x) {
    x = fminf(fmaxf(x, -10.0f), 10.0f);
    float a = __expf(2.0f * x);
    return (a - 1.0f) / (a + 1.0f);
}

__global__ __launch_bounds__(256) void decoder_fused(
    const float* __restrict__ y, const float* __restrict__ h0, const float* __restrict__ c0,
    const float* __restrict__ enc_out, const float* __restrict__ enc_feat,
    const float* __restrict__ W_ih, const float* __restrict__ W_hh,
    const float* __restrict__ b_ih, const float* __restrict__ b_hh,
    const float* __restrict__ W_proj, const float* __restrict__ b_proj,
    const float* __restrict__ v_w,
    const float* __restrict__ W1, const float* __restrict__ b1,
    const float* __restrict__ W2, const float* __restrict__ b2,
    float* __restrict__ out, int B, int T)
{
    const int b   = blockIdx.x;
    const int tid = threadIdx.x;
    const int lane = tid & 63;
    const int wid  = tid >> 6;

    __shared__ float s_h[HH];
    __shared__ float s_c[HH];
    __shared__ float s_gates[4 * HH];
    __shared__ float s_outin[2 * NN];   // [ s_t_hat(64) | c_t(64) ]
    __shared__ float s_decfea[NN];
    __shared__ float s_vw[NN];
    __shared__ float s_scores[TMAX];
    __shared__ float s_red[8];
    __shared__ float s_ct[16 * NN];     // 16 t-group partials of c_t

    // ---- Phase A: load state, LSTM step, projection (tiny) ----
    if (tid < HH) {
        s_h[tid] = h0[(size_t)b * HH + tid];
        s_c[tid] = c0[(size_t)b * HH + tid];
    }
    if (tid >= 64 && tid < 128) s_vw[tid - 64] = v_w[tid - 64];
    __syncthreads();

    if (tid < 4 * HH) {  // one gate per thread
        float acc = y[b] * W_ih[tid] + b_ih[tid] + b_hh[tid];
        const float* wr = W_hh + tid * HH;
        #pragma unroll
        for (int k = 0; k < HH; ++k) acc += wr[k] * s_h[k];
        s_gates[tid] = acc;
    }
    __syncthreads();

    if (tid < HH) {
        float ig = sigmoidf_(s_gates[tid]);
        float fg = sigmoidf_(s_gates[HH + tid]);
        float gg = ftanh(s_gates[2 * HH + tid]);
        float og = sigmoidf_(s_gates[3 * HH + tid]);
        float cn = fg * s_c[tid] + ig * gg;
        float hn = og * ftanh(cn);
        s_outin[tid]      = hn;   // s_t_hat = [h_new | c_new]
        s_outin[HH + tid] = cn;
        // outputs 1 and 2: h_new, c_new
        out[(size_t)B + (size_t)b * HH + tid]                   = hn;
        out[(size_t)B + (size_t)B * HH + (size_t)b * HH + tid]  = cn;
    }
    __syncthreads();

    if (tid < NN) {  // dec_fea = s_t_hat @ W_proj.T + b_proj
        float acc = b_proj[tid];
        const float* wr = W_proj + tid * NN;
        #pragma unroll
        for (int k = 0; k < NN; ++k) acc += wr[k] * s_outin[k];
        s_decfea[tid] = acc;
    }
    __syncthreads();

    // ---- Phase B: scores[t] = v_w . tanh(enc_feat[b,t,:] + dec_fea) ----
    const int tg = tid >> 4;   // 0..15 : t-offset within a group of 16 rows
    const int nc = tid & 15;   // 0..15 : float4 chunk within the 64-wide row
    const int n0 = nc * 4;
    const float4* ef = (const float4*)(enc_feat + (size_t)b * T * NN);
    const float vw0 = s_vw[n0], vw1 = s_vw[n0 + 1], vw2 = s_vw[n0 + 2], vw3 = s_vw[n0 + 3];
    const float df0 = s_decfea[n0], df1 = s_decfea[n0 + 1], df2 = s_decfea[n0 + 2], df3 = s_decfea[n0 + 3];

    for (int t0 = 0; t0 < T; t0 += 16) {
        int t = t0 + tg;
        float4 v = ef[t * 16 + nc];  // 64 lanes -> 1 KiB contiguous
        float p = vw0 * ftanh(v.x + df0) + vw1 * ftanh(v.y + df1)
                + vw2 * ftanh(v.z + df2) + vw3 * ftanh(v.w + df3);
        p += __shfl_xor(p, 1);
        p += __shfl_xor(p, 2);
        p += __shfl_xor(p, 4);
        p += __shfl_xor(p, 8);
        if (nc == 0) s_scores[t] = p;
    }
    __syncthreads();

    // ---- softmax over T ----
    float m = -3.4e38f;
    for (int t = tid; t < T; t += 256) m = fmaxf(m, s_scores[t]);
    #pragma unroll
    for (int mask = 32; mask >= 1; mask >>= 1) m = fmaxf(m, __shfl_xor(m, mask));
    if (lane == 0) s_red[wid] = m;
    __syncthreads();
    m = fmaxf(fmaxf(s_red[0], s_red[1]), fmaxf(s_red[2], s_red[3]));

    float lsum = 0.0f;
    for (int t = tid; t < T; t += 256) {
        float e = __expf(s_scores[t] - m);
        s_scores[t] = e;
        lsum += e;
    }
    #pragma unroll
    for (int mask = 32; mask >= 1; mask >>= 1) lsum += __shfl_xor(lsum, mask);
    if (lane == 0) s_red[4 + wid] = lsum;
    __syncthreads();
    const float inv = 1.0f / (s_red[4] + s_red[5] + s_red[6] + s_red[7]);
    for (int t = tid; t < T; t += 256) s_scores[t] *= inv;
    __syncthreads();

    // ---- Phase C: c_t = attn @ enc_out[b] ----
    const float4* eo = (const float4*)(enc_out + (size_t)b * T * NN);
    float ax = 0.f, ay = 0.f, az = 0.f, aw = 0.f;
    for (int t0 = 0; t0 < T; t0 += 16) {
        int t = t0 + tg;
        float a = s_scores[t];
        float4 v = eo[t * 16 + nc];
        ax += a * v.x; ay += a * v.y; az += a * v.z; aw += a * v.w;
    }
    s_ct[tg * NN + n0]     = ax;
    s_ct[tg * NN + n0 + 1] = ay;
    s_ct[tg * NN + n0 + 2] = az;
    s_ct[tg * NN + n0 + 3] = aw;
    __syncthreads();

    if (tid < NN) {
        float acc = 0.0f;
        #pragma unroll
        for (int g = 0; g < 16; ++g) acc += s_ct[g * NN + tid];
        s_outin[NN + tid] = acc;   // c_t
    }
    __syncthreads();

    // ---- Phase D: output MLP ----
    float v2 = 0.0f;
    if (tid < NN) {
        float acc = b1[tid];
        const float* wr = W1 + tid * 2 * NN;
        #pragma unroll
        for (int k = 0; k < 2 * NN; ++k) acc += wr[k] * s_outin[k];
        v2 = acc * W2[tid];
    }
    if (wid == 0) {  // tid<64 is exactly wave 0
        #pragma unroll
        for (int mask = 32; mask >= 1; mask >>= 1) v2 += __shfl_xor(v2, mask);
        if (tid == 0) out[b] = v2 + b2[0];
    }
}

extern "C" void kernel_launch(void* const* d_in, const int* in_sizes, int n_in,
                              void* d_out, int out_size, void* d_ws, size_t ws_size,
                              hipStream_t stream) {
    const float* y        = (const float*)d_in[0];
    const float* h0       = (const float*)d_in[1];
    const float* c0       = (const float*)d_in[2];
    const float* enc_out  = (const float*)d_in[3];
    const float* enc_feat = (const float*)d_in[4];
    const float* W_ih     = (const float*)d_in[5];
    const float* W_hh     = (const float*)d_in[6];
    const float* b_ih     = (const float*)d_in[7];
    const float* b_hh     = (const float*)d_in[8];
    const float* W_proj   = (const float*)d_in[9];
    const float* b_proj   = (const float*)d_in[10];
    const float* v_w      = (const float*)d_in[11];
    const float* W1       = (const float*)d_in[12];
    const float* b1       = (const float*)d_in[13];
    const float* W2       = (const float*)d_in[14];
    const float* b2       = (const float*)d_in[15];
    float* out = (float*)d_out;

    const int B = in_sizes[0];                 // y is (B,1)
    const int T = in_sizes[3] / (B * NN);      // encoder_outputs is (B,T,N)

    decoder_fused<<<B, 256, 0, stream>>>(
        y, h0, c0, enc_out, enc_feat, W_ih, W_hh, b_ih, b_hh,
        W_proj, b_proj, v_w, W1, b1, W2, b2, out, B, T);
}